// Round 2
// baseline (637.810 us; speedup 1.0000x reference)
//
#include <hip/hip_runtime.h>
#include <hip/hip_bf16.h>
#include <math.h>

// Problem constants (fixed by setup_inputs)
#define CIN      8
#define H_IN     100
#define W_IN     136
#define NPIX     (H_IN * W_IN)       // 13600
#define OH       (2 * H_IN)          // 200
#define OW       (2 * W_IN)          // 272
#define ONPIX    (OH * OW)           // 54400
#define NPARAMS  169
#define EPSV     1e-5f
#define NSLICE   4                   // row-slices per instance
#define PAIRS_PER_SLICE 25           // output row-pairs per slice (100/4)
#define KGROUPS  34                  // 272/8 col-groups
#define TASKS    (PAIRS_PER_SLICE * KGROUPS)   // 850

// param layout: w0[8][10] @0, w1[8][8] @80, w2[8] @144, b0 @152, b1 @160, b2 @168

__device__ __forceinline__ float sigmoidf_fast(float x) {
    float e = __expf(-x);
    return __builtin_amdgcn_rcpf(1.f + e);
}

__global__ __launch_bounds__(256, 4)
void mask_head_fused(const float* __restrict__ mask_feats,   // [N,8,100,136]
                     const float* __restrict__ params,       // [n,169]
                     const float* __restrict__ locs,         // [n,2]
                     const float* __restrict__ gt,           // [n,1,200,272]
                     const int*   __restrict__ im_inds,      // [n]
                     const int*   __restrict__ fpn_levels,   // [n]
                     float*       __restrict__ partials)     // [n*4][3]
{
    const int inst  = blockIdx.x >> 2;
    const int slice = blockIdx.x & 3;
    const int tid   = threadIdx.x;

    // src rows needed by this slice: pairs p = 25*slice .. 25*slice+24
    // -> src rows max(25*slice-1,0) .. 25*slice+24
    const int r_start = (slice == 0) ? 0 : 25 * slice - 1;
    const int r_end   = 25 * slice + 24;           // inclusive
    const int nrows   = r_end - r_start + 1;       // 25 (slice 0) or 26
    const int npx     = nrows * W_IN;              // <= 3536

    __shared__ float s_par[NPARAMS];
    __shared__ float s_logit[26 * W_IN];           // 14144 B
    __shared__ float s_red[12];

    if (tid < NPARAMS) s_par[tid] = params[inst * NPARAMS + tid];

    const int   im  = im_inds[inst];
    const int   lvl = fpn_levels[inst];
    const float inv_soi = exp2f(-(float)(3 + lvl));  // SOI = 8*2^lvl, exact
    const float lx = locs[inst * 2 + 0];
    const float ly = locs[inst * 2 + 1];

    __syncthreads();

    const float* feat = mask_feats + (size_t)im * (CIN * NPIX);
    const int goff = r_start * W_IN;   // global pixel offset of local pixel 0

    // ---------------- Phase A: logits for this slice's src rows -> LDS ----------------
    #pragma unroll 1
    for (int base = 0; base < 26 * W_IN; base += 1024) {
        const int p0 = base + tid;
        float in[10][4];
        #pragma unroll
        for (int k = 0; k < 4; ++k) {
            int p  = p0 + (k << 8);
            int pc = p < npx ? p : npx - 1;
            int r  = pc / W_IN;                 // local row
            int x  = pc - r * W_IN;
            int y  = r_start + r;
            in[0][k] = (lx - (float)(x * 8 + 4)) * inv_soi;
            in[1][k] = (ly - (float)(y * 8 + 4)) * inv_soi;
            int gp = goff + pc;
            #pragma unroll
            for (int c = 0; c < CIN; ++c)
                in[2 + c][k] = feat[c * NPIX + gp];
        }

        // layer 0: 10 -> 8, relu
        float h0[8][4];
        #pragma unroll
        for (int o = 0; o < 8; ++o) {
            float b = s_par[152 + o];
            float a0 = b, a1 = b, a2 = b, a3 = b;
            #pragma unroll
            for (int i = 0; i < 10; ++i) {
                float w = s_par[o * 10 + i];
                a0 = fmaf(w, in[i][0], a0);
                a1 = fmaf(w, in[i][1], a1);
                a2 = fmaf(w, in[i][2], a2);
                a3 = fmaf(w, in[i][3], a3);
            }
            h0[o][0] = fmaxf(a0, 0.f);
            h0[o][1] = fmaxf(a1, 0.f);
            h0[o][2] = fmaxf(a2, 0.f);
            h0[o][3] = fmaxf(a3, 0.f);
        }

        // layer 1: 8 -> 8, relu
        float h1[8][4];
        #pragma unroll
        for (int o = 0; o < 8; ++o) {
            float b = s_par[160 + o];
            float a0 = b, a1 = b, a2 = b, a3 = b;
            #pragma unroll
            for (int i = 0; i < 8; ++i) {
                float w = s_par[80 + o * 8 + i];
                a0 = fmaf(w, h0[i][0], a0);
                a1 = fmaf(w, h0[i][1], a1);
                a2 = fmaf(w, h0[i][2], a2);
                a3 = fmaf(w, h0[i][3], a3);
            }
            h1[o][0] = fmaxf(a0, 0.f);
            h1[o][1] = fmaxf(a1, 0.f);
            h1[o][2] = fmaxf(a2, 0.f);
            h1[o][3] = fmaxf(a3, 0.f);
        }

        // layer 2: 8 -> 1
        float b2 = s_par[168];
        float o0 = b2, o1 = b2, o2 = b2, o3 = b2;
        #pragma unroll
        for (int i = 0; i < 8; ++i) {
            float w = s_par[144 + i];
            o0 = fmaf(w, h1[i][0], o0);
            o1 = fmaf(w, h1[i][1], o1);
            o2 = fmaf(w, h1[i][2], o2);
            o3 = fmaf(w, h1[i][3], o3);
        }
        float outv[4] = {o0, o1, o2, o3};
        #pragma unroll
        for (int k = 0; k < 4; ++k) {
            int p = p0 + (k << 8);
            if (p < npx) s_logit[p] = outv[k];
        }
    }

    __syncthreads();

    // ---------------- Phase B: structured x2 upsample + sigmoid + dice ----------------
    // Output row 2p   = avg(src row p-1, src row p)   (p=0: src row 0)
    // Output row 2p+1 = src row p
    // Output cols per k-group (8 cols from src cols 4k-1..4k+3):
    //   o[0]=.5(S0+S1) o[1]=S1 o[2]=.5(S1+S2) o[3]=S2 o[4]=.5(S2+S3) o[5]=S3 o[6]=.5(S3+S4) o[7]=S4
    //   where S[j] = src col (4k-1+j), col -1 clamped to 0.
    float inter = 0.f, ssum = 0.f, tsum = 0.f;
    const float* gtp = gt + (size_t)inst * ONPIX;
    const int pair_base = 25 * slice;

    #pragma unroll 1
    for (int base = 0; base < TASKS; base += 256) {
        const int task = base + tid;
        if (task < TASKS) {
            const int pl = task / KGROUPS;
            const int k  = task - pl * KGROUPS;
            const int pg = pair_base + pl;
            const int er = pg - r_start;                       // exact src row (local)
            const int pr = (pg > 0 ? pg - 1 : 0) - r_start;    // prev src row (local)
            const float* E = s_logit + er * W_IN;
            const float* P = s_logit + pr * W_IN;
            const int c0  = 4 * k;
            const int cm1 = (k > 0) ? c0 - 1 : 0;

            const float4 e4 = *(const float4*)(E + c0);
            const float  em = E[cm1];
            const float4 p4 = *(const float4*)(P + c0);
            const float  pm = P[cm1];

            // S for exact row and avg row
            float Se[5] = {em, e4.x, e4.y, e4.z, e4.w};
            float Sa[5] = {0.5f * (em + pm), 0.5f * (e4.x + p4.x), 0.5f * (e4.y + p4.y),
                           0.5f * (e4.z + p4.z), 0.5f * (e4.w + p4.w)};

            float oa[8], oe[8];
            #pragma unroll
            for (int j = 0; j < 4; ++j) {
                oa[2 * j]     = 0.5f * (Sa[j] + Sa[j + 1]);
                oa[2 * j + 1] = Sa[j + 1];
                oe[2 * j]     = 0.5f * (Se[j] + Se[j + 1]);
                oe[2 * j + 1] = Se[j + 1];
            }

            const float* g0 = gtp + (size_t)(2 * pg) * OW + 8 * k;  // avg row
            const float4 ga = *(const float4*)(g0);
            const float4 gb = *(const float4*)(g0 + 4);
            const float4 gc = *(const float4*)(g0 + OW);
            const float4 gd = *(const float4*)(g0 + OW + 4);
            const float tva[8] = {ga.x, ga.y, ga.z, ga.w, gb.x, gb.y, gb.z, gb.w};
            const float tve[8] = {gc.x, gc.y, gc.z, gc.w, gd.x, gd.y, gd.z, gd.w};

            #pragma unroll
            for (int j = 0; j < 8; ++j) {
                float s = sigmoidf_fast(oa[j]);
                float t = tva[j];
                inter = fmaf(s, t, inter);
                ssum  = fmaf(s, s, ssum);
                tsum  = fmaf(t, t, tsum);
            }
            #pragma unroll
            for (int j = 0; j < 8; ++j) {
                float s = sigmoidf_fast(oe[j]);
                float t = tve[j];
                inter = fmaf(s, t, inter);
                ssum  = fmaf(s, s, ssum);
                tsum  = fmaf(t, t, tsum);
            }
        }
    }

    // block reduction (4 waves of 64)
    #pragma unroll
    for (int off = 32; off > 0; off >>= 1) {
        inter += __shfl_down(inter, off, 64);
        ssum  += __shfl_down(ssum,  off, 64);
        tsum  += __shfl_down(tsum,  off, 64);
    }
    const int wid = tid >> 6;
    if ((tid & 63) == 0) {
        s_red[wid * 3 + 0] = inter;
        s_red[wid * 3 + 1] = ssum;
        s_red[wid * 3 + 2] = tsum;
    }
    __syncthreads();
    if (tid == 0) {
        float I = 0.f, S = 0.f, T = 0.f;
        #pragma unroll
        for (int w = 0; w < 4; ++w) {
            I += s_red[w * 3 + 0];
            S += s_red[w * 3 + 1];
            T += s_red[w * 3 + 2];
        }
        partials[blockIdx.x * 3 + 0] = I;
        partials[blockIdx.x * 3 + 1] = S;
        partials[blockIdx.x * 3 + 2] = T;
    }
}

__global__ __launch_bounds__(512)
void loss_mean_kernel(const float* __restrict__ partials, float* __restrict__ out, int n)
{
    __shared__ float s_red[8];
    float v = 0.f;
    for (int i = threadIdx.x; i < n; i += 512) {
        float I = 0.f, S = 0.f, T = 0.f;
        #pragma unroll
        for (int s = 0; s < NSLICE; ++s) {
            const float* p = partials + (size_t)(i * NSLICE + s) * 3;
            I += p[0];
            S += p[1];
            T += p[2];
        }
        v += 1.f - 2.f * I / (S + T + EPSV);
    }
    #pragma unroll
    for (int off = 32; off > 0; off >>= 1) v += __shfl_down(v, off, 64);
    const int wid = threadIdx.x >> 6;
    if ((threadIdx.x & 63) == 0) s_red[wid] = v;
    __syncthreads();
    if (threadIdx.x == 0) {
        float s = 0.f;
        #pragma unroll
        for (int w = 0; w < 8; ++w) s += s_red[w];
        out[0] = s / (float)n;
    }
}

extern "C" void kernel_launch(void* const* d_in, const int* in_sizes, int n_in,
                              void* d_out, int out_size, void* d_ws, size_t ws_size,
                              hipStream_t stream)
{
    const float* mask_feats = (const float*)d_in[0];
    const float* params     = (const float*)d_in[1];
    const float* locs       = (const float*)d_in[2];
    const float* gt         = (const float*)d_in[3];
    const int*   im_inds    = (const int*)d_in[4];
    const int*   fpn_levels = (const int*)d_in[5];
    // d_in[6] = mask_feat_stride (always 8 for this problem)

    const int n = in_sizes[4];          // 500 instances
    float* partials = (float*)d_ws;     // n*NSLICE*3 floats

    mask_head_fused<<<n * NSLICE, 256, 0, stream>>>(mask_feats, params, locs, gt,
                                                    im_inds, fpn_levels, partials);
    loss_mean_kernel<<<1, 512, 0, stream>>>(partials, (float*)d_out, n);
}

// Round 3
// 204.401 us; speedup vs baseline: 3.1204x; 3.1204x over previous
//
#include <hip/hip_runtime.h>
#include <hip/hip_bf16.h>
#include <math.h>

// Problem constants (fixed by setup_inputs)
#define CIN      8
#define H_IN     100
#define W_IN     136
#define NPIX     (H_IN * W_IN)       // 13600
#define OH       (2 * H_IN)          // 200
#define OW       (2 * W_IN)          // 272
#define ONPIX    (OH * OW)           // 54400
#define NPARAMS  169
#define EPSV     1e-5f
#define NSLICE   4                   // row-slices per instance
#define PAIRS_PER_SLICE 25           // output row-pairs per slice (100/4)
#define KGROUPS  34                  // 272/8 col-groups
#define TASKS    (PAIRS_PER_SLICE * KGROUPS)   // 850

// param layout: w0[8][10] @0, w1[8][8] @80, w2[8] @144, b0 @152, b1 @160, b2 @168

__device__ __forceinline__ float sigmoidf_fast(float x) {
    float e = __expf(-x);
    return __builtin_amdgcn_rcpf(1.f + e);
}

// launch_bounds(256,2): round-1 evidence — 112 VGPR, no spill. (256,4) forced a
// 64-VGPR budget -> 1.8 GB of scratch spill traffic, 5x regression. Grid is now
// 2000 blocks, so ~4 blocks/CU comes from actual VGPR use, not the bound.
__global__ __launch_bounds__(256, 2)
void mask_head_fused(const float* __restrict__ mask_feats,   // [N,8,100,136]
                     const float* __restrict__ params,       // [n,169]
                     const float* __restrict__ locs,         // [n,2]
                     const float* __restrict__ gt,           // [n,1,200,272]
                     const int*   __restrict__ im_inds,      // [n]
                     const int*   __restrict__ fpn_levels,   // [n]
                     float*       __restrict__ partials)     // [n*4][3]
{
    const int inst  = blockIdx.x >> 2;
    const int slice = blockIdx.x & 3;
    const int tid   = threadIdx.x;

    // src rows needed by this slice: pairs p = 25*slice .. 25*slice+24
    // -> src rows max(25*slice-1,0) .. 25*slice+24
    const int r_start = (slice == 0) ? 0 : 25 * slice - 1;
    const int r_end   = 25 * slice + 24;           // inclusive
    const int nrows   = r_end - r_start + 1;       // 25 (slice 0) or 26
    const int npx     = nrows * W_IN;              // <= 3536

    __shared__ float s_par[NPARAMS];
    __shared__ float s_logit[26 * W_IN];           // 14144 B
    __shared__ float s_red[12];

    if (tid < NPARAMS) s_par[tid] = params[inst * NPARAMS + tid];

    const int   im  = im_inds[inst];
    const int   lvl = fpn_levels[inst];
    const float inv_soi = exp2f(-(float)(3 + lvl));  // SOI = 8*2^lvl, exact
    const float lx = locs[inst * 2 + 0];
    const float ly = locs[inst * 2 + 1];

    __syncthreads();

    const float* feat = mask_feats + (size_t)im * (CIN * NPIX);
    const int goff = r_start * W_IN;   // global pixel offset of local pixel 0

    // ---------------- Phase A: logits for this slice's src rows -> LDS ----------------
    #pragma unroll 1
    for (int base = 0; base < 26 * W_IN; base += 1024) {
        const int p0 = base + tid;
        float in[10][4];
        #pragma unroll
        for (int k = 0; k < 4; ++k) {
            int p  = p0 + (k << 8);
            int pc = p < npx ? p : npx - 1;
            int r  = pc / W_IN;                 // local row
            int x  = pc - r * W_IN;
            int y  = r_start + r;
            in[0][k] = (lx - (float)(x * 8 + 4)) * inv_soi;
            in[1][k] = (ly - (float)(y * 8 + 4)) * inv_soi;
            int gp = goff + pc;
            #pragma unroll
            for (int c = 0; c < CIN; ++c)
                in[2 + c][k] = feat[c * NPIX + gp];
        }

        // layer 0: 10 -> 8, relu
        float h0[8][4];
        #pragma unroll
        for (int o = 0; o < 8; ++o) {
            float b = s_par[152 + o];
            float a0 = b, a1 = b, a2 = b, a3 = b;
            #pragma unroll
            for (int i = 0; i < 10; ++i) {
                float w = s_par[o * 10 + i];
                a0 = fmaf(w, in[i][0], a0);
                a1 = fmaf(w, in[i][1], a1);
                a2 = fmaf(w, in[i][2], a2);
                a3 = fmaf(w, in[i][3], a3);
            }
            h0[o][0] = fmaxf(a0, 0.f);
            h0[o][1] = fmaxf(a1, 0.f);
            h0[o][2] = fmaxf(a2, 0.f);
            h0[o][3] = fmaxf(a3, 0.f);
        }

        // layer 1: 8 -> 8, relu
        float h1[8][4];
        #pragma unroll
        for (int o = 0; o < 8; ++o) {
            float b = s_par[160 + o];
            float a0 = b, a1 = b, a2 = b, a3 = b;
            #pragma unroll
            for (int i = 0; i < 8; ++i) {
                float w = s_par[80 + o * 8 + i];
                a0 = fmaf(w, h0[i][0], a0);
                a1 = fmaf(w, h0[i][1], a1);
                a2 = fmaf(w, h0[i][2], a2);
                a3 = fmaf(w, h0[i][3], a3);
            }
            h1[o][0] = fmaxf(a0, 0.f);
            h1[o][1] = fmaxf(a1, 0.f);
            h1[o][2] = fmaxf(a2, 0.f);
            h1[o][3] = fmaxf(a3, 0.f);
        }

        // layer 2: 8 -> 1
        float b2 = s_par[168];
        float o0 = b2, o1 = b2, o2 = b2, o3 = b2;
        #pragma unroll
        for (int i = 0; i < 8; ++i) {
            float w = s_par[144 + i];
            o0 = fmaf(w, h1[i][0], o0);
            o1 = fmaf(w, h1[i][1], o1);
            o2 = fmaf(w, h1[i][2], o2);
            o3 = fmaf(w, h1[i][3], o3);
        }
        float outv[4] = {o0, o1, o2, o3};
        #pragma unroll
        for (int k = 0; k < 4; ++k) {
            int p = p0 + (k << 8);
            if (p < npx) s_logit[p] = outv[k];
        }
    }

    __syncthreads();

    // ---------------- Phase B: structured x2 upsample + sigmoid + dice ----------------
    // Output row 2p   = avg(src row p-1, src row p)   (p=0: src row 0)
    // Output row 2p+1 = src row p
    // Output cols: o[2j]=avg of adjacent src cols, o[2j+1]=src col (left edge clamped)
    float inter = 0.f, ssum = 0.f, tsum = 0.f;
    const float* gtp = gt + (size_t)inst * ONPIX;
    const int pair_base = 25 * slice;

    #pragma unroll 1
    for (int base = 0; base < TASKS; base += 256) {
        const int task = base + tid;
        if (task < TASKS) {
            const int pl = task / KGROUPS;
            const int k  = task - pl * KGROUPS;
            const int pg = pair_base + pl;
            const int er = pg - r_start;                       // exact src row (local)
            const int pr = (pg > 0 ? pg - 1 : 0) - r_start;    // prev src row (local)
            const float* E = s_logit + er * W_IN;
            const float* P = s_logit + pr * W_IN;
            const int c0  = 4 * k;
            const int cm1 = (k > 0) ? c0 - 1 : 0;

            const float4 e4 = *(const float4*)(E + c0);
            const float  em = E[cm1];
            const float4 p4 = *(const float4*)(P + c0);
            const float  pm = P[cm1];

            const float* g0 = gtp + (size_t)(2 * pg) * OW + 8 * k;
            const float4 ga = *(const float4*)(g0);            // avg row, cols 0-3
            const float4 gb = *(const float4*)(g0 + 4);        // avg row, cols 4-7
            const float4 gc = *(const float4*)(g0 + OW);       // exact row, cols 0-3
            const float4 gd = *(const float4*)(g0 + OW + 4);   // exact row, cols 4-7

            const float ecur[4] = {e4.x, e4.y, e4.z, e4.w};
            const float pcur[4] = {p4.x, p4.y, p4.z, p4.w};
            const float gav[8]  = {ga.x, ga.y, ga.z, ga.w, gb.x, gb.y, gb.z, gb.w};
            const float gex[8]  = {gc.x, gc.y, gc.z, gc.w, gd.x, gd.y, gd.z, gd.w};

            float Se_prev = em;
            float Sa_prev = 0.5f * (em + pm);
            #pragma unroll
            for (int j = 0; j < 4; ++j) {
                const float Se = ecur[j];
                const float Sa = 0.5f * (ecur[j] + pcur[j]);
                // avg row: col 2j (avg), col 2j+1 (exact col)
                {
                    float s = sigmoidf_fast(0.5f * (Sa_prev + Sa));
                    float t = gav[2 * j];
                    inter = fmaf(s, t, inter); ssum = fmaf(s, s, ssum); tsum = fmaf(t, t, tsum);
                    s = sigmoidf_fast(Sa);
                    t = gav[2 * j + 1];
                    inter = fmaf(s, t, inter); ssum = fmaf(s, s, ssum); tsum = fmaf(t, t, tsum);
                }
                // exact row
                {
                    float s = sigmoidf_fast(0.5f * (Se_prev + Se));
                    float t = gex[2 * j];
                    inter = fmaf(s, t, inter); ssum = fmaf(s, s, ssum); tsum = fmaf(t, t, tsum);
                    s = sigmoidf_fast(Se);
                    t = gex[2 * j + 1];
                    inter = fmaf(s, t, inter); ssum = fmaf(s, s, ssum); tsum = fmaf(t, t, tsum);
                }
                Se_prev = Se;
                Sa_prev = Sa;
            }
        }
    }

    // block reduction (4 waves of 64)
    #pragma unroll
    for (int off = 32; off > 0; off >>= 1) {
        inter += __shfl_down(inter, off, 64);
        ssum  += __shfl_down(ssum,  off, 64);
        tsum  += __shfl_down(tsum,  off, 64);
    }
    const int wid = tid >> 6;
    if ((tid & 63) == 0) {
        s_red[wid * 3 + 0] = inter;
        s_red[wid * 3 + 1] = ssum;
        s_red[wid * 3 + 2] = tsum;
    }
    __syncthreads();
    if (tid == 0) {
        float I = 0.f, S = 0.f, T = 0.f;
        #pragma unroll
        for (int w = 0; w < 4; ++w) {
            I += s_red[w * 3 + 0];
            S += s_red[w * 3 + 1];
            T += s_red[w * 3 + 2];
        }
        partials[blockIdx.x * 3 + 0] = I;
        partials[blockIdx.x * 3 + 1] = S;
        partials[blockIdx.x * 3 + 2] = T;
    }
}

__global__ __launch_bounds__(512)
void loss_mean_kernel(const float* __restrict__ partials, float* __restrict__ out, int n)
{
    __shared__ float s_red[8];
    float v = 0.f;
    for (int i = threadIdx.x; i < n; i += 512) {
        float I = 0.f, S = 0.f, T = 0.f;
        #pragma unroll
        for (int s = 0; s < NSLICE; ++s) {
            const float* p = partials + (size_t)(i * NSLICE + s) * 3;
            I += p[0];
            S += p[1];
            T += p[2];
        }
        v += 1.f - 2.f * I / (S + T + EPSV);
    }
    #pragma unroll
    for (int off = 32; off > 0; off >>= 1) v += __shfl_down(v, off, 64);
    const int wid = threadIdx.x >> 6;
    if ((threadIdx.x & 63) == 0) s_red[wid] = v;
    __syncthreads();
    if (threadIdx.x == 0) {
        float s = 0.f;
        #pragma unroll
        for (int w = 0; w < 8; ++w) s += s_red[w];
        out[0] = s / (float)n;
    }
}

extern "C" void kernel_launch(void* const* d_in, const int* in_sizes, int n_in,
                              void* d_out, int out_size, void* d_ws, size_t ws_size,
                              hipStream_t stream)
{
    const float* mask_feats = (const float*)d_in[0];
    const float* params     = (const float*)d_in[1];
    const float* locs       = (const float*)d_in[2];
    const float* gt         = (const float*)d_in[3];
    const int*   im_inds    = (const int*)d_in[4];
    const int*   fpn_levels = (const int*)d_in[5];
    // d_in[6] = mask_feat_stride (always 8 for this problem)

    const int n = in_sizes[4];          // 500 instances
    float* partials = (float*)d_ws;     // n*NSLICE*3 floats

    mask_head_fused<<<n * NSLICE, 256, 0, stream>>>(mask_feats, params, locs, gt,
                                                    im_inds, fpn_levels, partials);
    loss_mean_kernel<<<1, 512, 0, stream>>>(partials, (float*)d_out, n);
}